// Round 4
// baseline (18417.303 us; speedup 1.0000x reference)
//
#include <hip/hip_runtime.h>
#include <cstdint>
#include <cstddef>

typedef unsigned short u16;
typedef unsigned int u32;
typedef __bf16 bf16x8 __attribute__((ext_vector_type(8)));
typedef float f32x16 __attribute__((ext_vector_type(16)));

// Tiled activation layout ("MFMA image"): unit(rb, kk, ks) = 512 u16 contiguous,
// ordered [khalf(2)][rl(32)][e(8)]; element (row, k): rb=row>>5, rl=row&31,
// kk=k>>5, ks=(k>>4)&1, khalf=(k>>3)&1, e=k&7.
// u16 index = ((rb*KK + kk)*2 + ks)*512 + khalf*256 + rl*8 + e.

// ---------- small helpers ----------
static __device__ __forceinline__ u16 f2b(float f) {
  u32 x = __builtin_bit_cast(u32, f);
  return (u16)((x + 0x7FFFu + ((x >> 16) & 1u)) >> 16);  // RNE
}
static __device__ __forceinline__ float blo(u32 w) {
  return __builtin_bit_cast(float, w << 16);
}
static __device__ __forceinline__ float bhi(u32 w) {
  return __builtin_bit_cast(float, w & 0xffff0000u);
}
static __device__ __forceinline__ void gl_lds16(const u16* g, u16* l) {
  __builtin_amdgcn_global_load_lds((const __attribute__((address_space(1))) u32*)g,
                                   (__attribute__((address_space(3))) u32*)l, 16, 0, 0);
}
static __device__ __forceinline__ f32x16 mfma16(bf16x8 a, bf16x8 b, f32x16 c) {
  return __builtin_amdgcn_mfma_f32_32x32x16_bf16(a, b, c, 0, 0, 0);
}
static __device__ __forceinline__ bf16x8 ldsfrag(const u16* p) {
  return *reinterpret_cast<const bf16x8*>(p);
}
static __device__ __forceinline__ f32x16 zero16() {
  f32x16 z;
#pragma unroll
  for (int i = 0; i < 16; ++i) z[i] = 0.0f;
  return z;
}
static __device__ __forceinline__ float sigm(float x) {
  return 1.0f / (1.0f + __expf(-x));
}
static __device__ __forceinline__ float tanh_fast(float x) {
  return 2.0f / (1.0f + __expf(-2.0f * x)) - 1.0f;
}
// tiled u16 index for a (row, col) element in a KK-wide tiled activation
static __device__ __forceinline__ size_t tidx(int row, int col, int KK) {
  return ((size_t)((row >> 5) * KK + (col >> 5)) * 2 + ((col >> 4) & 1)) * 512 +
         ((col >> 3) & 1) * 256 + (size_t)(row & 31) * 8 + (col & 7);
}

// ---------- weight packing ----------
// Tree blob, 128-wide N blocks. 16B units: [kk][nb][nt(4)][ksub(2)][khalf(2)][jl(32)]
__global__ void pack_tree(u16* __restrict__ dst, const float* __restrict__ src,
                          int NB, int K) {
  int u = blockIdx.x * 256 + threadIdx.x;
  int total = NB * 128 * (K / 8);
  if (u >= total) return;
  int u2 = u & 511;
  int q = u >> 9;
  int nb = q % NB, kk = q / NB;
  int jl = u2 & 31;
  int khalf = (u2 >> 5) & 1;
  int ksub = (u2 >> 6) & 1;
  int nt = (u2 >> 7) & 3;
  int row = nb * 128 + nt * 32 + jl;
  int kc = kk * 32 + ksub * 16 + khalf * 8;
  const float* s = src + (size_t)row * K + kc;
  u16 t[8];
#pragma unroll
  for (int e = 0; e < 8; ++e) t[e] = f2b(s[e]);
  u32 w0 = (u32)t[0] | ((u32)t[1] << 16);
  u32 w1 = (u32)t[2] | ((u32)t[3] << 16);
  u32 w2 = (u32)t[4] | ((u32)t[5] << 16);
  u32 w3 = (u32)t[6] | ((u32)t[7] << 16);
  *reinterpret_cast<uint4*>(dst + (size_t)u * 8) = make_uint4(w0, w1, w2, w3);
}

// GRU weight blob: [kk(34)][jb(16)][jg2(2)][s(3)][ksub(2)][khalf(2)][jl(32)]
__global__ void pack_gru(u16* __restrict__ dst, const float* __restrict__ Wih,
                         const float* __restrict__ Whh) {
  int u = blockIdx.x * 256 + threadIdx.x;
  if (u >= 34 * 16 * 768) return;
  int u2 = u % 768;
  int t = u / 768;
  int jb = t & 15, kk = t >> 4;
  int jl = u2 & 31;
  int q = u2 >> 5;
  int khalf = q & 1; q >>= 1;
  int ksub = q & 1; q >>= 1;
  int s = q % 3, jg2 = q / 3;
  int j = jb * 64 + jg2 * 32 + jl;
  int k = kk * 32 + ksub * 16 + khalf * 8;
  u16 tm[8];
  if (k < 64) {
    if (s == 2) {
#pragma unroll
      for (int e = 0; e < 8; ++e) tm[e] = 0;
    } else {
      const float* p = Wih + (size_t)(s * 1024 + j) * 64 + k;
#pragma unroll
      for (int e = 0; e < 8; ++e) tm[e] = f2b(p[e]);
    }
  } else {
    const float* p = Whh + (size_t)(s * 1024 + j) * 1024 + (k - 64);
#pragma unroll
    for (int e = 0; e < 8; ++e) tm[e] = f2b(p[e]);
  }
  u32 w0 = (u32)tm[0] | ((u32)tm[1] << 16);
  u32 w1 = (u32)tm[2] | ((u32)tm[3] << 16);
  u32 w2 = (u32)tm[4] | ((u32)tm[5] << 16);
  u32 w3 = (u32)tm[6] | ((u32)tm[7] << 16);
  *reinterpret_cast<uint4*>(dst + (size_t)u * 8) = make_uint4(w0, w1, w2, w3);
}

// W_ih n-gate blob: [kk(2)][jb(16)][jg2(2)][ksub(2)][khalf(2)][jl(32)]
__global__ void pack_ginn(u16* __restrict__ dst, const float* __restrict__ Wih) {
  int u = blockIdx.x * 256 + threadIdx.x;
  if (u >= 2 * 16 * 256) return;
  int u2 = u & 255;
  int t = u >> 8;
  int jb = t & 15, kk = t >> 4;
  int jl = u2 & 31;
  int khalf = (u2 >> 5) & 1;
  int ksub = (u2 >> 6) & 1;
  int jg2 = u2 >> 7;
  int j = jb * 64 + jg2 * 32 + jl;
  int k = kk * 32 + ksub * 16 + khalf * 8;
  const float* p = Wih + (size_t)(2048 + j) * 64 + k;
  u16 tm[8];
#pragma unroll
  for (int e = 0; e < 8; ++e) tm[e] = f2b(p[e]);
  u32 w0 = (u32)tm[0] | ((u32)tm[1] << 16);
  u32 w1 = (u32)tm[2] | ((u32)tm[3] << 16);
  u32 w2 = (u32)tm[4] | ((u32)tm[5] << 16);
  u32 w3 = (u32)tm[6] | ((u32)tm[7] << 16);
  *reinterpret_cast<uint4*>(dst + (size_t)u * 8) = make_uint4(w0, w1, w2, w3);
}

// k5 level-1 weights -> bf16 blob [64 rows][128 k]
__global__ void pack_w1(u16* __restrict__ dst,
                        const float* __restrict__ w_t, const float* __restrict__ w_la,
                        const float* __restrict__ w_ra, const float* __restrict__ w_ll,
                        const float* __restrict__ w_rl) {
  int i = blockIdx.x * 256 + threadIdx.x;
  if (i >= 8192) return;
  int rw = i >> 7, k = i & 127;
  float v;
  if (rw < 16) v = w_t[rw * 128 + k];
  else if (rw < 25) v = w_la[(rw - 16) * 128 + k];
  else if (rw < 34) v = w_ra[(rw - 25) * 128 + k];
  else if (rw < 49) v = w_ll[(rw - 34) * 128 + k];
  else v = w_rl[(rw - 49) * 128 + k];
  dst[i] = f2b(v);
}

__global__ void pack_bias(float* br, float* bz, float* bhn, float* bt3, float* bt4,
                          const float* b_ih, const float* b_hh,
                          const float* b3a, const float* b3l,
                          const float* b2ra, const float* b2la,
                          const float* b2rl, const float* b2ll) {
  int i = blockIdx.x * 256 + threadIdx.x;
  if (i >= 1024) return;
  br[i] = b_ih[i] + b_hh[i];
  bz[i] = b_ih[1024 + i] + b_hh[1024 + i];
  bhn[i] = b_hh[2048 + i];
  bt3[i] = (i < 512) ? b3a[i] : b3l[i - 512];
  int sg = i >> 8, sc = i & 255;
  const float* b2 = (sg == 0) ? b2ra : (sg == 1) ? b2la : (sg == 2) ? b2rl : b2ll;
  bt4[i] = b2[sc];
}

__global__ void init_h(float* __restrict__ hf, u16* __restrict__ hbT,
                       const float* __restrict__ h0) {
  size_t i = (size_t)blockIdx.x * 256 + threadIdx.x;
  int row = (int)(i >> 10), j = (int)(i & 1023);
  float v = h0[i];
  hf[i] = v;
  hbT[tidx(row, j, 32)] = f2b(v);
}

__global__ void init_x(float* __restrict__ xf, u16* __restrict__ xbT,
                       const float* __restrict__ gt) {
  int i = blockIdx.x * 256 + threadIdx.x;  // 4096*64
  int b = i >> 6, c = i & 63;
  float v = gt[(size_t)b * 128 * 64 + c];  // gt[:,0,:]
  xf[i] = v;
  xbT[tidx(b, c, 2)] = f2b(v);
}

// ---------- generic segment GEMM on tiled activations ----------
// block tile 128(M) x 128(N), 4 waves = 2m x 2n, wave 64x64 (4 acc).
// actT: tiled, KK=32. kkSeg: per-seg k-unit offset. out: tiled 1024-wide.
__global__ __launch_bounds__(256, 3) void tree_gemm(
    const u16* __restrict__ actT, int kkSeg,
    const u16* __restrict__ wblob, int nbPerSeg, int KS,
    const float* __restrict__ bias, u16* __restrict__ outp, int NperSeg) {
  __shared__ __align__(16) u16 lds[2][8192];  // per buf: A=4096 u16, B=4096 u16
  const int tid = threadIdx.x;
  const int lane = tid & 63, wave = tid >> 6;
  const int wm = wave >> 1, wn = wave & 1;
  // bijective XCD-chunked remap (gridDim.x==32, nwg%8==0)
  const int nwg = (int)(gridDim.x * gridDim.y);
  const int orig = (int)(blockIdx.x + blockIdx.y * 32);
  const int swz = (orig & 7) * (nwg >> 3) + (orig >> 3);
  const int bx = swz & 31, by = swz >> 5;

  const int mBase = bx * 128;
  const int rbBase = bx * 4;
  const int seg = by / nbPerSeg, nb = by % nbPerSeg;
  const int kkOff = seg * kkSeg;
  const u16* wseg = wblob + (size_t)seg * KS * nbPerSeg * 4096;
  const int outColBase = seg * NperSeg + nb * 128;

  f32x16 acc00 = zero16(), acc01 = zero16(), acc10 = zero16(), acc11 = zero16();

  auto stage = [&](int kk, int buf) {
    const u16* wsl = wseg + ((size_t)kk * nbPerSeg + nb) * 4096;
#pragma unroll
    for (int i = 0; i < 4; ++i) {
      int is = wave + 4 * i;
      if (is < 8) {
        int mt = is >> 1, ks = is & 1;
        const u16* g = actT +
            ((size_t)((rbBase + mt) * 32 + kkOff + kk) * 2 + ks) * 512 + lane * 8;
        gl_lds16(g, &lds[buf][is * 512]);
      } else {
        int b = is - 8;
        gl_lds16(wsl + (size_t)(b * 64 + lane) * 8, &lds[buf][4096 + b * 512]);
      }
    }
  };

  auto compute = [&](int buf) {
    const u16* L = lds[buf];
#pragma unroll
    for (int ks = 0; ks < 2; ++ks) {
      bf16x8 a0 = ldsfrag(L + ((wm * 2 + 0) * 2 + ks) * 512 + lane * 8);
      bf16x8 a1 = ldsfrag(L + ((wm * 2 + 1) * 2 + ks) * 512 + lane * 8);
      bf16x8 b0 = ldsfrag(L + 4096 + ((wn * 2 + 0) * 2 + ks) * 512 + lane * 8);
      bf16x8 b1 = ldsfrag(L + 4096 + ((wn * 2 + 1) * 2 + ks) * 512 + lane * 8);
      acc00 = mfma16(a0, b0, acc00);
      acc01 = mfma16(a0, b1, acc01);
      acc10 = mfma16(a1, b0, acc10);
      acc11 = mfma16(a1, b1, acc11);
    }
  };

  stage(0, 0);
  for (int kk = 0; kk < KS; ++kk) {
    __syncthreads();
    if (kk + 1 < KS) stage(kk + 1, (kk + 1) & 1);
    compute(kk & 1);
  }

  // epilogue: C/D layout col=lane&31, row=(r&3)+8*(r>>2)+4*(lane>>5); out tiled
#pragma unroll
  for (int mt = 0; mt < 2; ++mt) {
    int rbse = mBase + (wm * 2 + mt) * 32 + 4 * (lane >> 5);
#pragma unroll
    for (int ntl = 0; ntl < 2; ++ntl) {
      f32x16 c = (mt == 0) ? (ntl == 0 ? acc00 : acc01) : (ntl == 0 ? acc10 : acc11);
      int col = outColBase + wn * 64 + ntl * 32 + (lane & 31);
      float bv = bias[col];
#pragma unroll
      for (int r = 0; r < 16; ++r) {
        int row = rbse + (r & 3) + 8 * (r >> 2);
        outp[tidx(row, col, 32)] = f2b(c[r] + bv);
      }
    }
  }
}

// ---------- fused GRU: gates GEMM + inn GEMM (kk<2) + gate math ----------
// block tile 128(M) x 64(j) x 3 sets, 4 waves = 2m x 2jg. K=1088, KS=34.
__global__ __launch_bounds__(256, 2) void gru_gemm(
    const u16* __restrict__ xbT, const u16* __restrict__ hbT,
    float* __restrict__ hf, const u16* __restrict__ ginn,
    const u16* __restrict__ wgru,
    const float* __restrict__ br, const float* __restrict__ bz,
    const float* __restrict__ bhn, const float* __restrict__ bihn,
    u16* __restrict__ hbOutT) {
  __shared__ __align__(16) u16 lds[2][10240];  // per buf: A=4096, B=6144 u16
  __shared__ __align__(16) u16 ilds[4096];     // W_ihn tiles for kk=0,1
  const int tid = threadIdx.x;
  const int lane = tid & 63, wave = tid >> 6;
  const int wm = wave >> 1, wjg = wave & 1;
  // bijective XCD-chunked remap (gridDim.x==32, nwg=512)
  const int nwg = (int)(gridDim.x * gridDim.y);
  const int orig = (int)(blockIdx.x + blockIdx.y * 32);
  const int swz = (orig & 7) * (nwg >> 3) + (orig >> 3);
  const int bx = swz & 31, by = swz >> 5;

  const int mBase = bx * 128;
  const int rbBase = bx * 4;
  const int jb = by;

  f32x16 aR0 = zero16(), aZ0 = zero16(), aN0 = zero16(), aI0 = zero16();
  f32x16 aR1 = zero16(), aZ1 = zero16(), aN1 = zero16(), aI1 = zero16();

  auto stage = [&](int kk, int buf) {
#pragma unroll
    for (int i = 0; i < 5; ++i) {
      int is = wave + 4 * i;
      if (is < 8) {
        int mt = is >> 1, ks = is & 1;
        const u16* g;
        if (kk < 2)
          g = xbT + ((size_t)((rbBase + mt) * 2 + kk) * 2 + ks) * 512 + lane * 8;
        else
          g = hbT + ((size_t)((rbBase + mt) * 32 + (kk - 2)) * 2 + ks) * 512 + lane * 8;
        gl_lds16(g, &lds[buf][is * 512]);
      } else {
        int b = is - 8;
        const u16* g = wgru + ((size_t)(kk * 16 + jb) * 768 + b * 64 + lane) * 8;
        gl_lds16(g, &lds[buf][4096 + b * 512]);
      }
    }
  };

  // stage W_ihn tiles for kk=0 and kk=1 once (8 units)
  {
#pragma unroll
    for (int i = 0; i < 2; ++i) {
      int is = wave + 4 * i;
      int kk_i = is >> 2, r = is & 3;
      const u16* g = ginn + ((size_t)(kk_i * 16 + jb) * 2048) + r * 512 + lane * 8;
      gl_lds16(g, &ilds[is * 512]);
    }
  }

  auto compute = [&](int kk, int buf) {
    const u16* L = lds[buf];
    const u16* Bp = L + 4096;
#pragma unroll
    for (int ks = 0; ks < 2; ++ks) {
      bf16x8 a0 = ldsfrag(L + ((wm * 2 + 0) * 2 + ks) * 512 + lane * 8);
      bf16x8 a1 = ldsfrag(L + ((wm * 2 + 1) * 2 + ks) * 512 + lane * 8);
      bf16x8 bR = ldsfrag(Bp + ((wjg * 3 + 0) * 2 + ks) * 512 + lane * 8);
      bf16x8 bZ = ldsfrag(Bp + ((wjg * 3 + 1) * 2 + ks) * 512 + lane * 8);
      bf16x8 bN = ldsfrag(Bp + ((wjg * 3 + 2) * 2 + ks) * 512 + lane * 8);
      aR0 = mfma16(a0, bR, aR0);
      aZ0 = mfma16(a0, bZ, aZ0);
      aN0 = mfma16(a0, bN, aN0);
      aR1 = mfma16(a1, bR, aR1);
      aZ1 = mfma16(a1, bZ, aZ1);
      aN1 = mfma16(a1, bN, aN1);
      if (kk < 2) {
        bf16x8 bI = ldsfrag(ilds + kk * 2048 + (wjg * 2 + ks) * 512 + lane * 8);
        aI0 = mfma16(a0, bI, aI0);
        aI1 = mfma16(a1, bI, aI1);
      }
    }
  };

  stage(0, 0);
  for (int kk = 0; kk < 34; ++kk) {
    __syncthreads();
    if (kk + 1 < 34) stage(kk + 1, (kk + 1) & 1);
    compute(kk, kk & 1);
  }

  const int j = jb * 64 + wjg * 32 + (lane & 31);
  const float brv = br[j], bzv = bz[j], bhv = bhn[j], biv = bihn[j];
#pragma unroll
  for (int mt = 0; mt < 2; ++mt) {
    f32x16 cr = mt ? aR1 : aR0;
    f32x16 cz = mt ? aZ1 : aZ0;
    f32x16 cn = mt ? aN1 : aN0;
    f32x16 ci = mt ? aI1 : aI0;
    int rbse = mBase + (wm * 2 + mt) * 32 + 4 * (lane >> 5);
#pragma unroll
    for (int r = 0; r < 16; ++r) {
      int row = rbse + (r & 3) + 8 * (r >> 2);
      size_t idx = (size_t)row * 1024 + j;
      float rv = sigm(cr[r] + brv);
      float zv = sigm(cz[r] + bzv);
      float hnv = cn[r] + bhv;
      float inv = ci[r] + biv;
      float nv = tanh_fast(inv + rv * hnv);
      float ho = hf[idx];
      float hv = (1.0f - zv) * nv + zv * ho;
      hf[idx] = hv;
      hbOutT[tidx(row, j, 32)] = f2b(hv);
    }
  }
}

// ---------- level-1 limb layer + torso average + residual + output ----------
// 8 rows per block (512 blocks); de-tile lvl1T into [row][1024] LDS.
__global__ __launch_bounds__(256, 2) void k5_kernel(
    const u16* __restrict__ lvl1T, float* __restrict__ xf, u16* __restrict__ xbT,
    float* __restrict__ outp, int t, const u16* __restrict__ w1b,
    const float* __restrict__ b_t, const float* __restrict__ b_la,
    const float* __restrict__ b_ra, const float* __restrict__ b_ll,
    const float* __restrict__ b_rl) {
  __shared__ __align__(16) u16 wlds[64 * 128];
  __shared__ __align__(16) u16 alds[8 * 1024];
  const int tid = threadIdx.x;
  for (int i = tid; i < 1024; i += 256)
    *reinterpret_cast<uint4*>(wlds + i * 8) =
        *reinterpret_cast<const uint4*>(w1b + i * 8);
  const int rb = (blockIdx.x * 8) >> 5;
  const int rlb = (blockIdx.x * 8) & 31;
  for (int i = tid; i < 1024; i += 256) {
    int row = i & 7, cc = i >> 3;           // cc = k>>3: [kk(5)|ks|khalf]
    int kk = cc >> 2, ks = (cc >> 1) & 1, khalf = cc & 1;
    const u16* g = lvl1T + (((size_t)(rb * 32 + kk) * 2 + ks) * 2 + khalf) * 256 +
                   (size_t)(rlb + row) * 8;
    *reinterpret_cast<uint4*>(alds + ((size_t)row * 128 + cc) * 8) =
        *reinterpret_cast<const uint4*>(g);
  }
  __syncthreads();

  int rl = tid >> 6, c = tid & 63;
  int wrow, abase = 0, nseg = 1;
  float bv, scale = 1.0f;
  if (c < 13)      { wrow = c;             nseg = 4; scale = 0.25f; bv = b_t[c]; }
  else if (c < 22) { wrow = 16 + (c - 13); abase = 256; bv = b_la[c - 13]; }
  else if (c < 31) { wrow = 25 + (c - 22); abase = 0;   bv = b_ra[c - 22]; }
  else if (c < 46) { wrow = 34 + (c - 31); abase = 768; bv = b_ll[c - 31]; }
  else if (c < 61) { wrow = 49 + (c - 46); abase = 512; bv = b_rl[c - 46]; }
  else             { wrow = 13 + (c - 61); nseg = 4; scale = 0.25f; bv = b_t[13 + (c - 61)]; }

  float acc0 = 0.0f, acc1 = 0.0f;
  for (int s = 0; s < nseg; ++s) {
    int base = (nseg == 4) ? (128 + s * 256) : abase;
#pragma unroll
    for (int k8 = 0; k8 < 16; ++k8) {
      uint4 wv = *reinterpret_cast<const uint4*>(wlds + wrow * 128 + k8 * 8);
      uint4 a0 = *reinterpret_cast<const uint4*>(alds + rl * 1024 + base + k8 * 8);
      uint4 a1 = *reinterpret_cast<const uint4*>(alds + (rl + 4) * 1024 + base + k8 * 8);
      acc0 += blo(a0.x) * blo(wv.x) + bhi(a0.x) * bhi(wv.x)
            + blo(a0.y) * blo(wv.y) + bhi(a0.y) * bhi(wv.y)
            + blo(a0.z) * blo(wv.z) + bhi(a0.z) * bhi(wv.z)
            + blo(a0.w) * blo(wv.w) + bhi(a0.w) * bhi(wv.w);
      acc1 += blo(a1.x) * blo(wv.x) + bhi(a1.x) * bhi(wv.x)
            + blo(a1.y) * blo(wv.y) + bhi(a1.y) * bhi(wv.y)
            + blo(a1.z) * blo(wv.z) + bhi(a1.z) * bhi(wv.z)
            + blo(a1.w) * blo(wv.w) + bhi(a1.w) * bhi(wv.w);
    }
  }
#pragma unroll
  for (int pr = 0; pr < 2; ++pr) {
    int grow = blockIdx.x * 8 + rl + pr * 4;
    float acc = pr ? acc1 : acc0;
    size_t xi = (size_t)grow * 64 + c;
    float v = acc * scale + bv + xf[xi];
    outp[((size_t)grow * 128 + t) * 64 + c] = v;
    xf[xi] = v;
    xbT[tidx(grow, c, 2)] = f2b(v);
  }
}

// ---------- host ----------
extern "C" void kernel_launch(void* const* d_in, const int* in_sizes, int n_in,
                              void* d_out, int out_size, void* d_ws, size_t ws_size,
                              hipStream_t stream) {
  const float* h0   = (const float*)d_in[0];
  const float* gt   = (const float*)d_in[1];
  const float* Wih  = (const float*)d_in[2];
  const float* Whh  = (const float*)d_in[3];
  const float* bih  = (const float*)d_in[4];
  const float* bhh  = (const float*)d_in[5];
  const float* w4   = (const float*)d_in[6];
  const float* b4   = (const float*)d_in[7];
  const float* w3a  = (const float*)d_in[8];
  const float* b3a  = (const float*)d_in[9];
  const float* w3l  = (const float*)d_in[10];
  const float* b3l  = (const float*)d_in[11];
  const float* w2ra = (const float*)d_in[12];
  const float* b2ra = (const float*)d_in[13];
  const float* w2la = (const float*)d_in[14];
  const float* b2la = (const float*)d_in[15];
  const float* w2rl = (const float*)d_in[16];
  const float* b2rl = (const float*)d_in[17];
  const float* w2ll = (const float*)d_in[18];
  const float* b2ll = (const float*)d_in[19];
  const float* b1ra = (const float*)d_in[21];
  const float* b1la = (const float*)d_in[23];
  const float* b1rl = (const float*)d_in[25];
  const float* b1ll = (const float*)d_in[27];
  const float* w1ra = (const float*)d_in[20];
  const float* w1la = (const float*)d_in[22];
  const float* w1rl = (const float*)d_in[24];
  const float* w1ll = (const float*)d_in[26];
  const float* w1t  = (const float*)d_in[28];
  const float* b1t  = (const float*)d_in[29];
  float* out = (float*)d_out;

  char* ws = (char*)d_ws;
  size_t off = 0;
  auto alloc = [&](size_t b) {
    off = (off + 255) & ~(size_t)255;
    char* p = ws + off;
    off += b;
    return p;
  };

  float* hf  = (float*)alloc(4096UL * 1024 * 4);
  u16* hb0 = (u16*)alloc(4096UL * 1024 * 2);
  u16* hb1 = (u16*)alloc(4096UL * 1024 * 2);
  float* xf = (float*)alloc(4096UL * 64 * 4);
  u16* xb  = (u16*)alloc(4096UL * 64 * 2);
  u16* t0  = (u16*)alloc(4096UL * 1024 * 2);
  u16* t1  = (u16*)alloc(4096UL * 1024 * 2);
  u16* wgru = (u16*)alloc(34UL * 16 * 768 * 16);
  u16* ginn = (u16*)alloc(65536UL * 2);
  u16* wb4  = (u16*)alloc(32UL * 8 * 4096 * 2);
  u16* wb3  = (u16*)alloc(2UL * 16 * 4 * 4096 * 2);
  u16* wb2  = (u16*)alloc(4UL * 8 * 2 * 4096 * 2);
  u16* w1b  = (u16*)alloc(8192UL * 2);
  float* brp  = (float*)alloc(1024 * 4);
  float* bzp  = (float*)alloc(1024 * 4);
  float* bhnp = (float*)alloc(1024 * 4);
  float* bt3p = (float*)alloc(1024 * 4);
  float* bt4p = (float*)alloc(1024 * 4);
  (void)ws_size; (void)in_sizes; (void)n_in; (void)out_size;

  // ----- once-per-call prep -----
  pack_gru<<<dim3((34 * 16 * 768) / 256), 256, 0, stream>>>(wgru, Wih, Whh);
  pack_ginn<<<dim3(32), 256, 0, stream>>>(ginn, Wih);
  pack_tree<<<dim3(512), 256, 0, stream>>>(wb4, w4, 8, 1024);
  pack_tree<<<dim3(128), 256, 0, stream>>>(wb3, w3a, 4, 512);
  pack_tree<<<dim3(128), 256, 0, stream>>>(wb3 + 262144, w3l, 4, 512);
  pack_tree<<<dim3(32), 256, 0, stream>>>(wb2 + 0 * 65536, w2ra, 2, 256);
  pack_tree<<<dim3(32), 256, 0, stream>>>(wb2 + 1 * 65536, w2la, 2, 256);
  pack_tree<<<dim3(32), 256, 0, stream>>>(wb2 + 2 * 65536, w2rl, 2, 256);
  pack_tree<<<dim3(32), 256, 0, stream>>>(wb2 + 3 * 65536, w2ll, 2, 256);
  pack_w1<<<dim3(32), 256, 0, stream>>>(w1b, w1t, w1la, w1ra, w1ll, w1rl);
  pack_bias<<<dim3(4), 256, 0, stream>>>(brp, bzp, bhnp, bt3p, bt4p, bih, bhh,
                                         b3a, b3l, b2ra, b2la, b2rl, b2ll);
  init_h<<<dim3(16384), 256, 0, stream>>>(hf, hb0, h0);
  init_x<<<dim3(1024), 256, 0, stream>>>(xf, xb, gt);

  // ----- 128 sequential steps -----
  for (int t = 0; t < 128; ++t) {
    u16* hcur = (t & 1) ? hb1 : hb0;
    u16* hnext = (t & 1) ? hb0 : hb1;
    // K1: fused GRU (gates + inn) + update
    gru_gemm<<<dim3(32, 16), 256, 0, stream>>>(xb, hcur, hf, ginn, wgru,
                                               brp, bzp, bhnp, bih + 2048, hnext);
    // K2: fb = h @ w4^T + b4
    tree_gemm<<<dim3(32, 8), 256, 0, stream>>>(hnext, 0, wb4, 8, 32,
                                               b4, t0, 1024);
    // K3: ub|lb = fb halves @ w3_{arm,leg}^T  (seg k-offset 16 units = 512)
    tree_gemm<<<dim3(32, 8), 256, 0, stream>>>(t0, 16, wb3, 4, 16,
                                               bt3p, t1, 512);
    // K4: level-2 (4 segments of 256; seg k-offset 8 units)
    tree_gemm<<<dim3(32, 8), 256, 0, stream>>>(t1, 8, wb2, 2, 8,
                                               bt4p, t0, 256);
    // K5: limb layer + torso avg + residual + output write
    k5_kernel<<<dim3(512), 256, 0, stream>>>(t0, xf, xb, out, t, w1b,
                                             b1t, b1la, b1ra, b1ll, b1rl);
  }
}

// Round 5
// 8023.746 us; speedup vs baseline: 2.2953x; 2.2953x over previous
//
#include <hip/hip_runtime.h>
#include <cstdint>
#include <cstddef>

typedef unsigned short u16;
typedef unsigned int u32;
typedef __bf16 bf16x8 __attribute__((ext_vector_type(8)));
typedef float f32x16 __attribute__((ext_vector_type(16)));

// Tiled activation layout ("MFMA image"): unit(rb, kk, ks) = 512 u16 contiguous,
// ordered [khalf(2)][rl(32)][e(8)]; element (row, k): rb=row>>5, rl=row&31,
// kk=k>>5, ks=(k>>4)&1, khalf=(k>>3)&1, e=k&7.

// ---------- small helpers ----------
static __device__ __forceinline__ u16 f2b(float f) {
  u32 x = __builtin_bit_cast(u32, f);
  return (u16)((x + 0x7FFFu + ((x >> 16) & 1u)) >> 16);  // RNE
}
static __device__ __forceinline__ void gl_lds16(const u16* g, u16* l) {
  __builtin_amdgcn_global_load_lds((const __attribute__((address_space(1))) u32*)g,
                                   (__attribute__((address_space(3))) u32*)l, 16, 0, 0);
}
static __device__ __forceinline__ f32x16 mfma16(bf16x8 a, bf16x8 b, f32x16 c) {
  return __builtin_amdgcn_mfma_f32_32x32x16_bf16(a, b, c, 0, 0, 0);
}
static __device__ __forceinline__ bf16x8 ldsfrag(const u16* p) {
  return *reinterpret_cast<const bf16x8*>(p);
}
static __device__ __forceinline__ f32x16 zero16() {
  f32x16 z;
#pragma unroll
  for (int i = 0; i < 16; ++i) z[i] = 0.0f;
  return z;
}
static __device__ __forceinline__ float sigm(float x) {
  return 1.0f / (1.0f + __expf(-x));
}
static __device__ __forceinline__ float tanh_fast(float x) {
  return 2.0f / (1.0f + __expf(-2.0f * x)) - 1.0f;
}
static __device__ __forceinline__ size_t tidx(int row, int col, int KK) {
  return ((size_t)((row >> 5) * KK + (col >> 5)) * 2 + ((col >> 4) & 1)) * 512 +
         ((col >> 3) & 1) * 256 + (size_t)(row & 31) * 8 + (col & 7);
}

// ---------- one-time weight composition (fp32) ----------
// C[M x 1024] = A[M x K] @ B[K x 1024]; 64x64 tile per block, K-tiled via LDS.
__global__ void compose_gemm(float* __restrict__ C, const float* __restrict__ A,
                             const float* __restrict__ B, int K, int lda) {
  __shared__ float At[64][32];
  __shared__ float Bt[32][64];
  const int tid = threadIdx.x;
  const int rowBase = blockIdx.y * 64, colBase = blockIdx.x * 64;
  const int tx = tid & 15, ty = tid >> 4;
  float acc[4][4];
#pragma unroll
  for (int i = 0; i < 4; ++i)
#pragma unroll
    for (int j = 0; j < 4; ++j) acc[i][j] = 0.0f;

  for (int k0 = 0; k0 < K; k0 += 32) {
    for (int i = tid; i < 2048; i += 256) {
      At[i >> 5][i & 31] = A[(size_t)(rowBase + (i >> 5)) * lda + k0 + (i & 31)];
      Bt[i >> 6][i & 63] = B[(size_t)(k0 + (i >> 6)) * 1024 + colBase + (i & 63)];
    }
    __syncthreads();
#pragma unroll
    for (int kk = 0; kk < 32; ++kk) {
      float a[4], b[4];
#pragma unroll
      for (int i = 0; i < 4; ++i) a[i] = At[ty * 4 + i][kk];
#pragma unroll
      for (int j = 0; j < 4; ++j) b[j] = Bt[kk][tx * 4 + j];
#pragma unroll
      for (int i = 0; i < 4; ++i)
#pragma unroll
        for (int j = 0; j < 4; ++j) acc[i][j] += a[i] * b[j];
    }
    __syncthreads();
  }
#pragma unroll
  for (int i = 0; i < 4; ++i)
#pragma unroll
    for (int j = 0; j < 4; ++j)
      C[(size_t)(rowBase + ty * 4 + i) * 1024 + colBase + tx * 4 + j] = acc[i][j];
}

// Weff rows (padded to 128): out col order = [torso0-12 | la1(9) | ra1(9) | ll1(15) | rl1(15) | torso13-15]
__global__ void assemble_weff(float* __restrict__ dst, const float* __restrict__ A2,
                              const float* __restrict__ w1t, const float* __restrict__ w1la,
                              const float* __restrict__ w1ra, const float* __restrict__ w1ll,
                              const float* __restrict__ w1rl) {
  int idx = blockIdx.x * 256 + threadIdx.x;  // 128*1024
  int r = idx >> 10, col = idx & 1023;
  if (r >= 64) { dst[idx] = 0.0f; return; }
  float acc = 0.0f;
  if (r < 13 || r >= 61) {
    int tr = (r < 13) ? r : 13 + (r - 61);
    for (int k = 0; k < 128; ++k) {
      float s = A2[(size_t)(128 + k) * 1024 + col] + A2[(size_t)(384 + k) * 1024 + col] +
                A2[(size_t)(640 + k) * 1024 + col] + A2[(size_t)(896 + k) * 1024 + col];
      acc += w1t[tr * 128 + k] * s;
    }
    acc *= 0.25f;
  } else if (r < 22) {
    const float* w = w1la + (r - 13) * 128;
    for (int k = 0; k < 128; ++k) acc += w[k] * A2[(size_t)(256 + k) * 1024 + col];
  } else if (r < 31) {
    const float* w = w1ra + (r - 22) * 128;
    for (int k = 0; k < 128; ++k) acc += w[k] * A2[(size_t)k * 1024 + col];
  } else if (r < 46) {
    const float* w = w1ll + (r - 31) * 128;
    for (int k = 0; k < 128; ++k) acc += w[k] * A2[(size_t)(768 + k) * 1024 + col];
  } else {
    const float* w = w1rl + (r - 46) * 128;
    for (int k = 0; k < 128; ++k) acc += w[k] * A2[(size_t)(512 + k) * 1024 + col];
  }
  dst[idx] = acc;
}

// beff: propagate biases through the affine tree. One block, 1024 threads.
__global__ void compose_bias(float* __restrict__ beff,
    const float* w3a, const float* w3l, const float* b4, const float* b3a, const float* b3l,
    const float* w2ra, const float* b2ra, const float* w2la, const float* b2la,
    const float* w2rl, const float* b2rl, const float* w2ll, const float* b2ll,
    const float* w1t, const float* b1t, const float* w1la, const float* b1la,
    const float* w1ra, const float* b1ra, const float* w1ll, const float* b1ll,
    const float* w1rl, const float* b1rl) {
  __shared__ float v1[1024], v2[1024];
  int i = threadIdx.x;
  {
    float a = 0.0f;
    if (i < 512) {
      for (int k = 0; k < 512; ++k) a += w3a[i * 512 + k] * b4[k];
      a += b3a[i];
    } else {
      int r = i - 512;
      for (int k = 0; k < 512; ++k) a += w3l[r * 512 + k] * b4[512 + k];
      a += b3l[r];
    }
    v1[i] = a;
  }
  __syncthreads();
  {
    int seg = i >> 8, r = i & 255;
    const float* w = seg == 0 ? w2ra : seg == 1 ? w2la : seg == 2 ? w2rl : w2ll;
    const float* bb = seg == 0 ? b2ra : seg == 1 ? b2la : seg == 2 ? b2rl : b2ll;
    float a = 0.0f;
    for (int k = 0; k < 256; ++k) a += w[r * 256 + k] * v1[seg * 256 + k];
    v2[i] = a + bb[r];
  }
  __syncthreads();
  if (i < 64) {
    float a = 0.0f;
    if (i < 13 || i >= 61) {
      int tr = (i < 13) ? i : 13 + (i - 61);
      for (int k = 0; k < 128; ++k)
        a += w1t[tr * 128 + k] * (v2[128 + k] + v2[384 + k] + v2[640 + k] + v2[896 + k]);
      a = a * 0.25f + b1t[tr];
    } else if (i < 22) {
      int r = i - 13;
      for (int k = 0; k < 128; ++k) a += w1la[r * 128 + k] * v2[256 + k];
      a += b1la[r];
    } else if (i < 31) {
      int r = i - 22;
      for (int k = 0; k < 128; ++k) a += w1ra[r * 128 + k] * v2[k];
      a += b1ra[r];
    } else if (i < 46) {
      int r = i - 31;
      for (int k = 0; k < 128; ++k) a += w1ll[r * 128 + k] * v2[768 + k];
      a += b1ll[r];
    } else {
      int r = i - 46;
      for (int k = 0; k < 128; ++k) a += w1rl[r * 128 + k] * v2[512 + k];
      a += b1rl[r];
    }
    beff[i] = a;
  }
}

// ---------- weight packing ----------
// Tree-style blob. 16B units: [kk][nb][nt(4)][ksub(2)][khalf(2)][jl(32)]
__global__ void pack_tree(u16* __restrict__ dst, const float* __restrict__ src,
                          int NB, int K) {
  int u = blockIdx.x * 256 + threadIdx.x;
  int total = NB * 128 * (K / 8);
  if (u >= total) return;
  int u2 = u & 511;
  int q = u >> 9;
  int nb = q % NB, kk = q / NB;
  int jl = u2 & 31;
  int khalf = (u2 >> 5) & 1;
  int ksub = (u2 >> 6) & 1;
  int nt = (u2 >> 7) & 3;
  int row = nb * 128 + nt * 32 + jl;
  int kc = kk * 32 + ksub * 16 + khalf * 8;
  const float* s = src + (size_t)row * K + kc;
  u16 t[8];
#pragma unroll
  for (int e = 0; e < 8; ++e) t[e] = f2b(s[e]);
  u32 w0 = (u32)t[0] | ((u32)t[1] << 16);
  u32 w1 = (u32)t[2] | ((u32)t[3] << 16);
  u32 w2 = (u32)t[4] | ((u32)t[5] << 16);
  u32 w3 = (u32)t[6] | ((u32)t[7] << 16);
  *reinterpret_cast<uint4*>(dst + (size_t)u * 8) = make_uint4(w0, w1, w2, w3);
}

// GRU weight blob: [kk(34)][jb(16)][jg2(2)][s(3)][ksub(2)][khalf(2)][jl(32)]
__global__ void pack_gru(u16* __restrict__ dst, const float* __restrict__ Wih,
                         const float* __restrict__ Whh) {
  int u = blockIdx.x * 256 + threadIdx.x;
  if (u >= 34 * 16 * 768) return;
  int u2 = u % 768;
  int t = u / 768;
  int jb = t & 15, kk = t >> 4;
  int jl = u2 & 31;
  int q = u2 >> 5;
  int khalf = q & 1; q >>= 1;
  int ksub = q & 1; q >>= 1;
  int s = q % 3, jg2 = q / 3;
  int j = jb * 64 + jg2 * 32 + jl;
  int k = kk * 32 + ksub * 16 + khalf * 8;
  u16 tm[8];
  if (k < 64) {
    if (s == 2) {
#pragma unroll
      for (int e = 0; e < 8; ++e) tm[e] = 0;
    } else {
      const float* p = Wih + (size_t)(s * 1024 + j) * 64 + k;
#pragma unroll
      for (int e = 0; e < 8; ++e) tm[e] = f2b(p[e]);
    }
  } else {
    const float* p = Whh + (size_t)(s * 1024 + j) * 1024 + (k - 64);
#pragma unroll
    for (int e = 0; e < 8; ++e) tm[e] = f2b(p[e]);
  }
  u32 w0 = (u32)tm[0] | ((u32)tm[1] << 16);
  u32 w1 = (u32)tm[2] | ((u32)tm[3] << 16);
  u32 w2 = (u32)tm[4] | ((u32)tm[5] << 16);
  u32 w3 = (u32)tm[6] | ((u32)tm[7] << 16);
  *reinterpret_cast<uint4*>(dst + (size_t)u * 8) = make_uint4(w0, w1, w2, w3);
}

// W_ih n-gate blob: [kk(2)][jb(16)][jg2(2)][ksub(2)][khalf(2)][jl(32)]
__global__ void pack_ginn(u16* __restrict__ dst, const float* __restrict__ Wih) {
  int u = blockIdx.x * 256 + threadIdx.x;
  if (u >= 2 * 16 * 256) return;
  int u2 = u & 255;
  int t = u >> 8;
  int jb = t & 15, kk = t >> 4;
  int jl = u2 & 31;
  int khalf = (u2 >> 5) & 1;
  int ksub = (u2 >> 6) & 1;
  int jg2 = u2 >> 7;
  int j = jb * 64 + jg2 * 32 + jl;
  int k = kk * 32 + ksub * 16 + khalf * 8;
  const float* p = Wih + (size_t)(2048 + j) * 64 + k;
  u16 tm[8];
#pragma unroll
  for (int e = 0; e < 8; ++e) tm[e] = f2b(p[e]);
  u32 w0 = (u32)tm[0] | ((u32)tm[1] << 16);
  u32 w1 = (u32)tm[2] | ((u32)tm[3] << 16);
  u32 w2 = (u32)tm[4] | ((u32)tm[5] << 16);
  u32 w3 = (u32)tm[6] | ((u32)tm[7] << 16);
  *reinterpret_cast<uint4*>(dst + (size_t)u * 8) = make_uint4(w0, w1, w2, w3);
}

__global__ void pack_bias_gru(float* br, float* bz, float* bhn,
                              const float* b_ih, const float* b_hh) {
  int i = blockIdx.x * 256 + threadIdx.x;
  if (i >= 1024) return;
  br[i] = b_ih[i] + b_hh[i];
  bz[i] = b_ih[1024 + i] + b_hh[1024 + i];
  bhn[i] = b_hh[2048 + i];
}

__global__ void init_h(float* __restrict__ hf, u16* __restrict__ hbT,
                       const float* __restrict__ h0) {
  size_t i = (size_t)blockIdx.x * 256 + threadIdx.x;
  int row = (int)(i >> 10), j = (int)(i & 1023);
  float v = h0[i];
  hf[i] = v;
  hbT[tidx(row, j, 32)] = f2b(v);
}

__global__ void init_x(float* __restrict__ xf, u16* __restrict__ xbT,
                       const float* __restrict__ gt) {
  int i = blockIdx.x * 256 + threadIdx.x;  // 4096*64
  int b = i >> 6, c = i & 63;
  float v = gt[(size_t)b * 128 * 64 + c];  // gt[:,0,:]
  xf[i] = v;
  xbT[tidx(b, c, 2)] = f2b(v);
}

// ---------- fused GRU: gates GEMM + inn GEMM (kk<2) + gate math ----------
// block tile 128(M) x 64(j) x 3 sets, 4 waves = 2m x 2jg. K=1088, KS=34.
__global__ __launch_bounds__(256, 2) void gru_gemm(
    const u16* __restrict__ xbT, const u16* __restrict__ hbT,
    float* __restrict__ hf, const u16* __restrict__ ginn,
    const u16* __restrict__ wgru,
    const float* __restrict__ br, const float* __restrict__ bz,
    const float* __restrict__ bhn, const float* __restrict__ bihn,
    u16* __restrict__ hbOutT) {
  __shared__ __align__(16) u16 lds[2][10240];  // per buf: A=4096, B=6144 u16
  __shared__ __align__(16) u16 ilds[4096];     // W_ihn tiles for kk=0,1
  const int tid = threadIdx.x;
  const int lane = tid & 63, wave = tid >> 6;
  const int wm = wave >> 1, wjg = wave & 1;
  // bijective XCD-chunked remap (nwg=512)
  const int nwg = (int)(gridDim.x * gridDim.y);
  const int orig = (int)(blockIdx.x + blockIdx.y * 32);
  const int swz = (orig & 7) * (nwg >> 3) + (orig >> 3);
  const int bx = swz & 31, by = swz >> 5;

  const int mBase = bx * 128;
  const int rbBase = bx * 4;
  const int jb = by;

  f32x16 aR0 = zero16(), aZ0 = zero16(), aN0 = zero16(), aI0 = zero16();
  f32x16 aR1 = zero16(), aZ1 = zero16(), aN1 = zero16(), aI1 = zero16();

  auto stage = [&](int kk, int buf) {
#pragma unroll
    for (int i = 0; i < 5; ++i) {
      int is = wave + 4 * i;
      if (is < 8) {
        int mt = is >> 1, ks = is & 1;
        const u16* g;
        if (kk < 2)
          g = xbT + ((size_t)((rbBase + mt) * 2 + kk) * 2 + ks) * 512 + lane * 8;
        else
          g = hbT + ((size_t)((rbBase + mt) * 32 + (kk - 2)) * 2 + ks) * 512 + lane * 8;
        gl_lds16(g, &lds[buf][is * 512]);
      } else {
        int b = is - 8;
        const u16* g = wgru + ((size_t)(kk * 16 + jb) * 768 + b * 64 + lane) * 8;
        gl_lds16(g, &lds[buf][4096 + b * 512]);
      }
    }
  };

  {
#pragma unroll
    for (int i = 0; i < 2; ++i) {
      int is = wave + 4 * i;
      int kk_i = is >> 2, r = is & 3;
      const u16* g = ginn + ((size_t)(kk_i * 16 + jb) * 2048) + r * 512 + lane * 8;
      gl_lds16(g, &ilds[is * 512]);
    }
  }

  auto compute = [&](int kk, int buf) {
    const u16* L = lds[buf];
    const u16* Bp = L + 4096;
#pragma unroll
    for (int ks = 0; ks < 2; ++ks) {
      bf16x8 a0 = ldsfrag(L + ((wm * 2 + 0) * 2 + ks) * 512 + lane * 8);
      bf16x8 a1 = ldsfrag(L + ((wm * 2 + 1) * 2 + ks) * 512 + lane * 8);
      bf16x8 bR = ldsfrag(Bp + ((wjg * 3 + 0) * 2 + ks) * 512 + lane * 8);
      bf16x8 bZ = ldsfrag(Bp + ((wjg * 3 + 1) * 2 + ks) * 512 + lane * 8);
      bf16x8 bN = ldsfrag(Bp + ((wjg * 3 + 2) * 2 + ks) * 512 + lane * 8);
      aR0 = mfma16(a0, bR, aR0);
      aZ0 = mfma16(a0, bZ, aZ0);
      aN0 = mfma16(a0, bN, aN0);
      aR1 = mfma16(a1, bR, aR1);
      aZ1 = mfma16(a1, bZ, aZ1);
      aN1 = mfma16(a1, bN, aN1);
      if (kk < 2) {
        bf16x8 bI = ldsfrag(ilds + kk * 2048 + (wjg * 2 + ks) * 512 + lane * 8);
        aI0 = mfma16(a0, bI, aI0);
        aI1 = mfma16(a1, bI, aI1);
      }
    }
  };

  stage(0, 0);
  for (int kk = 0; kk < 34; ++kk) {
    __syncthreads();
    if (kk + 1 < 34) stage(kk + 1, (kk + 1) & 1);
    compute(kk, kk & 1);
  }

  const int j = jb * 64 + wjg * 32 + (lane & 31);
  const float brv = br[j], bzv = bz[j], bhv = bhn[j], biv = bihn[j];
#pragma unroll
  for (int mt = 0; mt < 2; ++mt) {
    f32x16 cr = mt ? aR1 : aR0;
    f32x16 cz = mt ? aZ1 : aZ0;
    f32x16 cn = mt ? aN1 : aN0;
    f32x16 ci = mt ? aI1 : aI0;
    int rbse = mBase + (wm * 2 + mt) * 32 + 4 * (lane >> 5);
#pragma unroll
    for (int r = 0; r < 16; ++r) {
      int row = rbse + (r & 3) + 8 * (r >> 2);
      size_t idx = (size_t)row * 1024 + j;
      float rv = sigm(cr[r] + brv);
      float zv = sigm(cz[r] + bzv);
      float hnv = cn[r] + bhv;
      float inv = ci[r] + biv;
      float nv = tanh_fast(inv + rv * hnv);
      float ho = hf[idx];
      float hv = (1.0f - zv) * nv + zv * ho;
      hf[idx] = hv;
      hbOutT[tidx(row, j, 32)] = f2b(hv);
    }
  }
}

// ---------- cell GEMM: x += h @ Weff^T + beff; write out[:, t, :], xf, xbT ----------
// block 64 rows x 64 cols, 4 waves = 2m x 2n (each 32x32, 1 acc). K=1024 (KS=32).
__global__ __launch_bounds__(256, 4) void cell_gemm(
    const u16* __restrict__ hbT, const u16* __restrict__ wbE,
    const float* __restrict__ beff, float* __restrict__ xf,
    u16* __restrict__ xbT, float* __restrict__ outp, int t) {
  __shared__ __align__(16) u16 lds[2][4096];  // per buf: A=2048, B=2048 u16
  const int tid = threadIdx.x;
  const int lane = tid & 63, wave = tid >> 6;
  const int wm = wave >> 1, wn = wave & 1;
  const int rbBase = blockIdx.x * 2;  // 64 rows per block

  f32x16 acc = zero16();

  auto stage = [&](int kk, int buf) {
    {  // A unit: (rb_loc = wave>>1, ks = wave&1)
      int rb_loc = wave >> 1, ks = wave & 1;
      const u16* g = hbT + ((size_t)((rbBase + rb_loc) * 32 + kk) * 2 + ks) * 512 + lane * 8;
      gl_lds16(g, &lds[buf][wave * 512]);
    }
    {  // B unit: (nt = wave>>1, ks = wave&1) -> blob offset (nt*2+ks)*512 = wave*512
      const u16* g = wbE + (size_t)kk * 4096 + (size_t)wave * 512 + lane * 8;
      gl_lds16(g, &lds[buf][2048 + wave * 512]);
    }
  };

  auto compute = [&](int buf) {
    const u16* L = lds[buf];
#pragma unroll
    for (int ks = 0; ks < 2; ++ks) {
      bf16x8 a = ldsfrag(L + (wm * 2 + ks) * 512 + lane * 8);
      bf16x8 b = ldsfrag(L + 2048 + (wn * 2 + ks) * 512 + lane * 8);
      acc = mfma16(a, b, acc);
    }
  };

  stage(0, 0);
  for (int kk = 0; kk < 32; ++kk) {
    __syncthreads();
    if (kk + 1 < 32) stage(kk + 1, (kk + 1) & 1);
    compute(kk & 1);
  }

  const int col = wn * 32 + (lane & 31);
  const float bv = beff[col];
  const int rbse = rbBase * 32 + wm * 32 + 4 * (lane >> 5);
#pragma unroll
  for (int r = 0; r < 16; ++r) {
    int row = rbse + (r & 3) + 8 * (r >> 2);
    size_t xi = (size_t)row * 64 + col;
    float v = acc[r] + bv + xf[xi];
    xf[xi] = v;
    outp[((size_t)row * 128 + t) * 64 + col] = v;
    xbT[tidx(row, col, 2)] = f2b(v);
  }
}

// ---------- host ----------
extern "C" void kernel_launch(void* const* d_in, const int* in_sizes, int n_in,
                              void* d_out, int out_size, void* d_ws, size_t ws_size,
                              hipStream_t stream) {
  const float* h0   = (const float*)d_in[0];
  const float* gt   = (const float*)d_in[1];
  const float* Wih  = (const float*)d_in[2];
  const float* Whh  = (const float*)d_in[3];
  const float* bih  = (const float*)d_in[4];
  const float* bhh  = (const float*)d_in[5];
  const float* w4   = (const float*)d_in[6];
  const float* b4   = (const float*)d_in[7];
  const float* w3a  = (const float*)d_in[8];
  const float* b3a  = (const float*)d_in[9];
  const float* w3l  = (const float*)d_in[10];
  const float* b3l  = (const float*)d_in[11];
  const float* w2ra = (const float*)d_in[12];
  const float* b2ra = (const float*)d_in[13];
  const float* w2la = (const float*)d_in[14];
  const float* b2la = (const float*)d_in[15];
  const float* w2rl = (const float*)d_in[16];
  const float* b2rl = (const float*)d_in[17];
  const float* w2ll = (const float*)d_in[18];
  const float* b2ll = (const float*)d_in[19];
  const float* w1ra = (const float*)d_in[20];
  const float* b1ra = (const float*)d_in[21];
  const float* w1la = (const float*)d_in[22];
  const float* b1la = (const float*)d_in[23];
  const float* w1rl = (const float*)d_in[24];
  const float* b1rl = (const float*)d_in[25];
  const float* w1ll = (const float*)d_in[26];
  const float* b1ll = (const float*)d_in[27];
  const float* w1t  = (const float*)d_in[28];
  const float* b1t  = (const float*)d_in[29];
  float* out = (float*)d_out;

  char* ws = (char*)d_ws;
  size_t off = 0;
  auto alloc = [&](size_t b) {
    off = (off + 255) & ~(size_t)255;
    char* p = ws + off;
    off += b;
    return p;
  };

  float* hf   = (float*)alloc(4096UL * 1024 * 4);
  u16* hb0    = (u16*)alloc(4096UL * 1024 * 2);
  u16* hb1    = (u16*)alloc(4096UL * 1024 * 2);
  float* xf   = (float*)alloc(4096UL * 64 * 4);
  u16* xb     = (u16*)alloc(4096UL * 64 * 2);
  u16* wgru   = (u16*)alloc(34UL * 16 * 768 * 16);
  u16* ginn   = (u16*)alloc(65536UL * 2);
  float* A1   = (float*)alloc(1024UL * 1024 * 4);
  float* A2   = (float*)alloc(1024UL * 1024 * 4);
  float* weffp= (float*)alloc(128UL * 1024 * 4);
  u16* wbE    = (u16*)alloc(128UL * 1024 * 2);
  float* brp  = (float*)alloc(1024 * 4);
  float* bzp  = (float*)alloc(1024 * 4);
  float* bhnp = (float*)alloc(1024 * 4);
  float* beff = (float*)alloc(64 * 4);
  (void)ws_size; (void)in_sizes; (void)n_in; (void)out_size;

  // ----- once-per-call prep -----
  pack_gru<<<dim3((34 * 16 * 768) / 256), 256, 0, stream>>>(wgru, Wih, Whh);
  pack_ginn<<<dim3(32), 256, 0, stream>>>(ginn, Wih);
  // A1 = w3blk @ w4
  compose_gemm<<<dim3(16, 8), 256, 0, stream>>>(A1, w3a, w4, 512, 512);
  compose_gemm<<<dim3(16, 8), 256, 0, stream>>>(A1 + 512 * 1024, w3l, w4 + 512 * 1024, 512, 512);
  // A2 = w2blk @ A1
  compose_gemm<<<dim3(16, 4), 256, 0, stream>>>(A2, w2ra, A1, 256, 256);
  compose_gemm<<<dim3(16, 4), 256, 0, stream>>>(A2 + 256 * 1024, w2la, A1 + 256 * 1024, 256, 256);
  compose_gemm<<<dim3(16, 4), 256, 0, stream>>>(A2 + 512 * 1024, w2rl, A1 + 512 * 1024, 256, 256);
  compose_gemm<<<dim3(16, 4), 256, 0, stream>>>(A2 + 768 * 1024, w2ll, A1 + 768 * 1024, 256, 256);
  // Weff (padded to 128 rows) + beff
  assemble_weff<<<dim3(512), 256, 0, stream>>>(weffp, A2, w1t, w1la, w1ra, w1ll, w1rl);
  compose_bias<<<dim3(1), 1024, 0, stream>>>(beff, w3a, w3l, b4, b3a, b3l,
                                             w2ra, b2ra, w2la, b2la, w2rl, b2rl, w2ll, b2ll,
                                             w1t, b1t, w1la, b1la, w1ra, b1ra,
                                             w1ll, b1ll, w1rl, b1rl);
  pack_tree<<<dim3(64), 256, 0, stream>>>(wbE, weffp, 1, 1024);
  pack_bias_gru<<<dim3(4), 256, 0, stream>>>(brp, bzp, bhnp, bih, bhh);
  init_h<<<dim3(16384), 256, 0, stream>>>(hf, hb0, h0);
  init_x<<<dim3(1024), 256, 0, stream>>>(xf, xb, gt);

  // ----- 128 sequential steps: 2 kernels/step -----
  for (int t = 0; t < 128; ++t) {
    u16* hcur = (t & 1) ? hb1 : hb0;
    u16* hnext = (t & 1) ? hb0 : hb1;
    gru_gemm<<<dim3(32, 16), 256, 0, stream>>>(xb, hcur, hf, ginn, wgru,
                                               brp, bzp, bhnp, bih + 2048, hnext);
    cell_gemm<<<dim3(64), 256, 0, stream>>>(hnext, wbE, beff, xf, xb, out, t);
  }
}